// Round 1
// baseline (429.199 us; speedup 1.0000x reference)
//
#include <hip/hip_runtime.h>
#include <math.h>

#define BN 4
#define DD 256
#define LL 4096
#define NS 16
#define NCH 32   // scan chunks
#define CT 128   // chunk length (NCH*CT == LL)

__device__ __forceinline__ float softplus_f(float v) {
  return v > 20.f ? v : log1pf(__expf(v));
}
__device__ __forceinline__ float silu_f(float v) {
  return v / (1.f + __expf(-v));
}

// ---------------- K1: xz = in_proj_w (512x256) @ U[b] (256x4096) ----------------
// 128x128 tile, 8x8 per thread, K-step 16.
__global__ __launch_bounds__(256) void k1_inproj(
    const float* __restrict__ W, const float* __restrict__ U,
    float* __restrict__ xpre, float* __restrict__ zb) {
  __shared__ float Wt[16][128];  // [k][e]
  __shared__ float Ut[16][128];  // [k][l]
  const int l0 = blockIdx.x * 128;
  const int e0 = blockIdx.y * 128;
  const int b  = blockIdx.z;
  const int tid = threadIdx.x;
  const int tx = tid & 15, ty = tid >> 4;
  const float* Ub = U + (size_t)b * DD * LL;
  float acc[8][8];
#pragma unroll
  for (int i = 0; i < 8; ++i)
#pragma unroll
    for (int j = 0; j < 8; ++j) acc[i][j] = 0.f;

  for (int k0 = 0; k0 < DD; k0 += 16) {
#pragma unroll
    for (int i = 0; i < 2; ++i) {
      int idx = tid * 8 + i * 4;        // 2048 = 128e x 16k
      int e = idx >> 4, kk = idx & 15;
      float4 v = *(const float4*)(W + (size_t)(e0 + e) * DD + k0 + kk);
      Wt[kk + 0][e] = v.x; Wt[kk + 1][e] = v.y;
      Wt[kk + 2][e] = v.z; Wt[kk + 3][e] = v.w;
    }
#pragma unroll
    for (int i = 0; i < 2; ++i) {
      int idx = tid * 4 + i * 1024;     // 2048 = 16k x 128l
      int kk = idx >> 7, l = idx & 127;
      *(float4*)&Ut[kk][l] = *(const float4*)(Ub + (size_t)(k0 + kk) * LL + l0 + l);
    }
    __syncthreads();
#pragma unroll
    for (int kk = 0; kk < 16; ++kk) {
      float a[8], bb2[8];
#pragma unroll
      for (int i = 0; i < 4; ++i) { a[i] = Wt[kk][ty * 4 + i]; a[i + 4] = Wt[kk][64 + ty * 4 + i]; }
#pragma unroll
      for (int j = 0; j < 4; ++j) { bb2[j] = Ut[kk][tx * 4 + j]; bb2[j + 4] = Ut[kk][64 + tx * 4 + j]; }
#pragma unroll
      for (int i = 0; i < 8; ++i)
#pragma unroll
        for (int j = 0; j < 8; ++j) acc[i][j] += a[i] * bb2[j];
    }
    __syncthreads();
  }
#pragma unroll
  for (int i = 0; i < 8; ++i) {
    int e = e0 + ((i < 4) ? (ty * 4 + i) : (64 + ty * 4 + (i - 4)));
    float* dst = (e < DD) ? (xpre + ((size_t)b * DD + e) * LL)
                          : (zb   + ((size_t)b * DD + (e - DD)) * LL);
    float4 v0 = make_float4(acc[i][0], acc[i][1], acc[i][2], acc[i][3]);
    float4 v1 = make_float4(acc[i][4], acc[i][5], acc[i][6], acc[i][7]);
    *(float4*)(dst + l0 + tx * 4) = v0;
    *(float4*)(dst + l0 + 64 + tx * 4) = v1;
  }
}

// ---------------- K2: depthwise conv == 3-tap along d, weights per l ----------------
__global__ __launch_bounds__(256) void k2_conv(
    const float* __restrict__ xpre, const float* __restrict__ cw,
    const float* __restrict__ cb, float* __restrict__ xo) {
  const int bd = blockIdx.x;       // b*256 + d
  const int d = bd & 255;
  const size_t row = (size_t)bd * LL;
  const float* r1 = xpre + row;
  const bool has0 = d > 0, has2 = d < DD - 1;
  for (int j = threadIdx.x; j < LL; j += 256) {
    float w0 = cw[j * 9 + 3], w1 = cw[j * 9 + 4], w2 = cw[j * 9 + 5];
    float v = cb[j] + r1[j] * w1;
    if (has0) v += r1[j - LL] * w0;
    if (has2) v += r1[j + LL] * w2;
    xo[row + j] = v;
  }
}

// ---------------- K3: x_proj + dt_proj (both dirs), softplus delta, B, C ----------------
__global__ __launch_bounds__(256) void k3_proj(
    const float* __restrict__ x,
    const float* __restrict__ xpw,  const float* __restrict__ dtw,
    const float* __restrict__ dtb,
    const float* __restrict__ xpwB, const float* __restrict__ dtwB,
    float* __restrict__ gdelta, float* __restrict__ gB, float* __restrict__ gC) {
  __shared__ float xt[DD][32];
  __shared__ float dbls[2][48][32];
  const int l0 = blockIdx.x * 32;
  const int b = blockIdx.y;
  const int tid = threadIdx.x;
  const int j = tid & 31, grp = tid >> 5;

  for (int base = tid; base < DD * 32; base += 256) {
    int dd = base >> 5, jj = base & 31;
    xt[dd][jj] = x[((size_t)b * DD + dd) * LL + l0 + jj];
  }
  __syncthreads();

  for (int dir = 0; dir < 2; ++dir) {
    const float* wp = dir ? xpwB : xpw;
    float acc[6] = {0.f, 0.f, 0.f, 0.f, 0.f, 0.f};
#pragma unroll 4
    for (int dd = 0; dd < DD; ++dd) {
      float xv = xt[dd][j];
#pragma unroll
      for (int ki = 0; ki < 6; ++ki)
        acc[ki] += wp[(size_t)(grp + ki * 8) * DD + dd] * xv;
    }
#pragma unroll
    for (int ki = 0; ki < 6; ++ki) dbls[dir][grp + ki * 8][j] = acc[ki];
  }
  __syncthreads();

  for (int dir = 0; dir < 2; ++dir) {
    const float* dw = dir ? dtwB : dtw;
    for (int dd = grp * 32; dd < grp * 32 + 32; ++dd) {
      float acc = 0.f;
#pragma unroll
      for (int r = 0; r < 16; ++r) acc += dw[dd * 16 + r] * dbls[dir][r][j];
      float delta = softplus_f(acc + dtb[dd]);
      gdelta[(((size_t)dir * BN + b) * DD + dd) * LL + l0 + j] = delta;
    }
  }
  for (int idx = tid; idx < 2 * 32 * 32; idx += 256) {
    int dir = idx >> 10;
    int rem = idx & 1023;
    int k = rem >> 5, jj = rem & 31;
    float v = dbls[dir][16 + k][jj];
    if (k < 16)
      gB[(((size_t)dir * BN + b) * NS + k) * LL + l0 + jj] = v;
    else
      gC[(((size_t)dir * BN + b) * NS + (k - 16)) * LL + l0 + jj] = v;
  }
}

// ---------------- K4: scan pass A — per-chunk P = prod(dA), q = chunk scan from 0 ----------------
__global__ __launch_bounds__(256) void k4_scanA(
    const float* __restrict__ gdelta, const float* __restrict__ x,
    const float* __restrict__ gB,
    const float* __restrict__ Alog, const float* __restrict__ AlogB,
    float* __restrict__ Pbuf, float* __restrict__ qbuf) {
  __shared__ float sdelta[16][CT + 1];
  __shared__ float sx[16][CT + 1];
  __shared__ float sB[16][CT + 1];
  const int s = blockIdx.x;
  const int dbase = blockIdx.y * 16;
  const int dir = blockIdx.z >> 2, b = blockIdx.z & 3;
  const int t0 = s * CT;
  const int tid = threadIdx.x;

  for (int idx = tid; idx < 16 * CT; idx += 256) {
    int row = idx >> 7, jj = idx & (CT - 1);
    sdelta[row][jj] = gdelta[(((size_t)dir * BN + b) * DD + dbase + row) * LL + t0 + jj];
    int tt = dir ? (LL - 1 - (t0 + jj)) : (t0 + jj);
    sx[row][jj] = x[((size_t)b * DD + dbase + row) * LL + tt];
    sB[row][jj] = gB[(((size_t)dir * BN + b) * NS + row) * LL + t0 + jj];
  }
  __syncthreads();

  const int g = tid >> 4, n = tid & 15;
  const int d = dbase + g;
  const float* Al = dir ? AlogB : Alog;
  const float An = -__expf(Al[d * NS + n]);
  float h = 0.f, P = 1.f;
#pragma unroll 4
  for (int jj = 0; jj < CT; ++jj) {
    float dl = sdelta[g][jj];
    float xv = sx[g][jj];
    float Bn = sB[n][jj];
    float dA = __expf(dl * An);
    h = h * dA + dl * xv * Bn;
    P *= dA;
  }
  const size_t pidx = ((((size_t)dir * BN + b) * DD + d) * NCH + s) * NS + n;
  Pbuf[pidx] = P;
  qbuf[pidx] = h;
}

// ---------------- K5: middle scan over chunks; hstart overwrites qbuf in place ----------------
__global__ __launch_bounds__(256) void k5_mid(
    const float* __restrict__ Pbuf, float* __restrict__ qbuf) {
  int id = blockIdx.x * 256 + threadIdx.x;   // 32768 = 2*4*256*16
  int n = id & 15;
  int d = (id >> 4) & 255;
  int rb = id >> 12;                         // dir*4 + b
  size_t base = (((size_t)rb * DD + d) * NCH) * NS + n;
  float h = 0.f;
  for (int s = 0; s < NCH; ++s) {
    size_t idx = base + (size_t)s * NS;
    float Pv = Pbuf[idx];
    float qv = qbuf[idx];
    qbuf[idx] = h;            // exclusive prefix: state at chunk start
    h = h * Pv + qv;
  }
}

// ---------------- K6: scan pass C — replay with correct h0, emit gated y ----------------
__global__ __launch_bounds__(256) void k6_scanC(
    const float* __restrict__ gdelta, const float* __restrict__ x,
    const float* __restrict__ gB, const float* __restrict__ gC,
    const float* __restrict__ zb,
    const float* __restrict__ Alog, const float* __restrict__ AlogB,
    const float* __restrict__ Dvec, const float* __restrict__ DvecB,
    const float* __restrict__ hstart,
    float* __restrict__ y, float* __restrict__ yb) {
  __shared__ float sdelta[16][CT + 1];
  __shared__ float sx[16][CT + 1];
  __shared__ float sB[16][CT + 1];
  __shared__ float sC[16][CT + 1];
  const int s = blockIdx.x;
  const int dbase = blockIdx.y * 16;
  const int dir = blockIdx.z >> 2, b = blockIdx.z & 3;
  const int t0 = s * CT;
  const int tid = threadIdx.x;

  for (int idx = tid; idx < 16 * CT; idx += 256) {
    int row = idx >> 7, jj = idx & (CT - 1);
    sdelta[row][jj] = gdelta[(((size_t)dir * BN + b) * DD + dbase + row) * LL + t0 + jj];
    int tt = dir ? (LL - 1 - (t0 + jj)) : (t0 + jj);
    sx[row][jj] = x[((size_t)b * DD + dbase + row) * LL + tt];
    sB[row][jj] = gB[(((size_t)dir * BN + b) * NS + row) * LL + t0 + jj];
    sC[row][jj] = gC[(((size_t)dir * BN + b) * NS + row) * LL + t0 + jj];
  }
  __syncthreads();

  const int g = tid >> 4, n = tid & 15;
  const int d = dbase + g;
  const float* Al = dir ? AlogB : Alog;
  const float An = -__expf(Al[d * NS + n]);
  const float Dd = (dir ? DvecB : Dvec)[d];
  const size_t pidx = ((((size_t)dir * BN + b) * DD + d) * NCH + s) * NS + n;
  float h = hstart[pidx];
  float* dst = (dir ? yb : y) + ((size_t)b * DD + d) * LL;
  const float* zrow = zb + ((size_t)b * DD + d) * LL;

  for (int jb = 0; jb < CT; jb += 16) {
    float ykeep = 0.f;
#pragma unroll
    for (int jj2 = 0; jj2 < 16; ++jj2) {
      int jj = jb + jj2;
      float dl = sdelta[g][jj];
      float xv = sx[g][jj];
      float Bn = sB[n][jj];
      float Cn = sC[n][jj];
      float dA = __expf(dl * An);
      h = h * dA + dl * xv * Bn;
      float yc = h * Cn;
      yc += __shfl_xor(yc, 1);
      yc += __shfl_xor(yc, 2);
      yc += __shfl_xor(yc, 4);
      yc += __shfl_xor(yc, 8);
      if (jj2 == n) ykeep = yc;   // lane n keeps step jb+n -> coalesced store
    }
    float xv = sx[g][jb + n];
    float zv = zrow[t0 + jb + n];
    dst[t0 + jb + n] = (ykeep + Dd * xv) * silu_f(zv);
  }
}

// ---------------- K7: dual LayerNorm over l + double SiLU gate + flip-add ----------------
__global__ __launch_bounds__(256) void k7_final(
    const float* __restrict__ y, const float* __restrict__ yb,
    const float* __restrict__ zb,
    const float* __restrict__ lnw, const float* __restrict__ lnb,
    const float* __restrict__ ln1w, const float* __restrict__ ln1b,
    float* __restrict__ out) {
  __shared__ float sy[LL];
  __shared__ float syb[LL];
  __shared__ float rsum[4][4];
  const int row = blockIdx.x;           // b*256 + d
  const int tid = threadIdx.x;
  const size_t base = (size_t)row * LL;
  float s1y = 0.f, s2y = 0.f, s1b = 0.f, s2b = 0.f;
  for (int j = tid * 4; j < LL; j += 1024) {
    float4 v = *(const float4*)(y + base + j);
    *(float4*)&sy[j] = v;
    s1y += v.x + v.y + v.z + v.w;
    s2y += v.x * v.x + v.y * v.y + v.z * v.z + v.w * v.w;
    float4 w = *(const float4*)(yb + base + j);
    *(float4*)&syb[j] = w;
    s1b += w.x + w.y + w.z + w.w;
    s2b += w.x * w.x + w.y * w.y + w.z * w.z + w.w * w.w;
  }
#pragma unroll
  for (int m = 1; m < 64; m <<= 1) {
    s1y += __shfl_xor(s1y, m); s2y += __shfl_xor(s2y, m);
    s1b += __shfl_xor(s1b, m); s2b += __shfl_xor(s2b, m);
  }
  int wv = tid >> 6;
  if ((tid & 63) == 0) { rsum[wv][0] = s1y; rsum[wv][1] = s2y; rsum[wv][2] = s1b; rsum[wv][3] = s2b; }
  __syncthreads();
  float t1y = rsum[0][0] + rsum[1][0] + rsum[2][0] + rsum[3][0];
  float t2y = rsum[0][1] + rsum[1][1] + rsum[2][1] + rsum[3][1];
  float t1b = rsum[0][2] + rsum[1][2] + rsum[2][2] + rsum[3][2];
  float t2b = rsum[0][3] + rsum[1][3] + rsum[2][3] + rsum[3][3];
  const float inv = 1.f / (float)LL;
  float mY = t1y * inv; float vY = t2y * inv - mY * mY; float rY = rsqrtf(vY + 1e-5f);
  float mB = t1b * inv; float vB = t2b * inv - mB * mB; float rB = rsqrtf(vB + 1e-5f);
  for (int j = tid; j < LL; j += 256) {
    int jr = LL - 1 - j;
    float a  = (sy[j]  - mY) * rY * lnw[j]   + lnb[j];
    float g1 = silu_f(zb[base + j]);
    float bv = (syb[jr] - mB) * rB * ln1w[jr] + ln1b[jr];
    float g2 = silu_f(zb[base + jr]);
    out[base + j] = a * g1 + bv * g2;
  }
}

extern "C" void kernel_launch(void* const* d_in, const int* in_sizes, int n_in,
                              void* d_out, int out_size, void* d_ws, size_t ws_size,
                              hipStream_t stream) {
  const float* u     = (const float*)d_in[0];
  const float* inw   = (const float*)d_in[1];
  const float* cw    = (const float*)d_in[2];
  const float* cb    = (const float*)d_in[3];
  const float* xpw   = (const float*)d_in[4];
  const float* dtw   = (const float*)d_in[5];
  const float* dtb   = (const float*)d_in[6];
  const float* Alog  = (const float*)d_in[7];
  const float* Dv    = (const float*)d_in[8];
  const float* xpwB  = (const float*)d_in[9];
  const float* dtwB  = (const float*)d_in[10];
  const float* AlogB = (const float*)d_in[11];
  const float* DvB   = (const float*)d_in[12];
  const float* lnw   = (const float*)d_in[13];
  const float* lnb   = (const float*)d_in[14];
  const float* ln1w  = (const float*)d_in[15];
  const float* ln1b  = (const float*)d_in[16];
  float* out = (float*)d_out;

  float* ws = (float*)d_ws;
  const size_t SZ = (size_t)BN * DD * LL;        // 4,194,304 floats
  float* xpre   = ws;                 // reused as y after k2/k3 consume it
  float* zb     = ws + SZ;
  float* xc     = ws + 2 * SZ;
  float* gdelta = ws + 3 * SZ;        // 2 dirs -> 2*SZ
  float* gB     = ws + 5 * SZ;        // 2*4*16*4096 = SZ/8
  float* gC     = gB + SZ / 8;
  float* Pbuf   = gC + SZ / 8;        // 2*4*256*32*16 = SZ/4
  float* qbuf   = Pbuf + SZ / 4;      // doubles as hstart after k5_mid
  float* ybuf   = xpre;               // alias: xpre dead after k2
  float* ybbuf  = qbuf + SZ / 4;      // total: 6.75*SZ floats ~ 108 MB

  k1_inproj<<<dim3(32, 4, 4), 256, 0, stream>>>(inw, u, xpre, zb);
  k2_conv<<<1024, 256, 0, stream>>>(xpre, cw, cb, xc);
  k3_proj<<<dim3(128, 4), 256, 0, stream>>>(xc, xpw, dtw, dtb, xpwB, dtwB, gdelta, gB, gC);
  k4_scanA<<<dim3(NCH, 16, 8), 256, 0, stream>>>(gdelta, xc, gB, Alog, AlogB, Pbuf, qbuf);
  k5_mid<<<128, 256, 0, stream>>>(Pbuf, qbuf);
  k6_scanC<<<dim3(NCH, 16, 8), 256, 0, stream>>>(gdelta, xc, gB, gC, zb, Alog, AlogB,
                                                 Dv, DvB, qbuf, ybuf, ybbuf);
  k7_final<<<1024, 256, 0, stream>>>(ybuf, ybbuf, zb, lnw, lnb, ln1w, ln1b, out);
}

// Round 2
// 359.264 us; speedup vs baseline: 1.1947x; 1.1947x over previous
//
#include <hip/hip_runtime.h>
#include <math.h>

#define BN 4
#define DD 256
#define LL 4096
#define NS 16
#define NCH 32   // scan chunks
#define CT 128   // chunk length (NCH*CT == LL)
#define SP 132   // CT + 4 pad: keeps 16B alignment, spreads 16 rows over banks

__device__ __forceinline__ float softplus_f(float v) {
  return v > 20.f ? v : log1pf(__expf(v));
}
__device__ __forceinline__ float silu_f(float v) {
  return v / (1.f + __expf(-v));
}

// ---------------- K1: xz = in_proj_w (512x256) @ U[b] (256x4096) ----------------
__global__ __launch_bounds__(256) void k1_inproj(
    const float* __restrict__ W, const float* __restrict__ U,
    float* __restrict__ xpre, float* __restrict__ zb) {
  __shared__ float Wt[16][128];  // [k][e]
  __shared__ float Ut[16][128];  // [k][l]
  const int l0 = blockIdx.x * 128;
  const int e0 = blockIdx.y * 128;
  const int b  = blockIdx.z;
  const int tid = threadIdx.x;
  const int tx = tid & 15, ty = tid >> 4;
  const float* Ub = U + (size_t)b * DD * LL;
  float acc[8][8];
#pragma unroll
  for (int i = 0; i < 8; ++i)
#pragma unroll
    for (int j = 0; j < 8; ++j) acc[i][j] = 0.f;

  for (int k0 = 0; k0 < DD; k0 += 16) {
#pragma unroll
    for (int i = 0; i < 2; ++i) {
      int idx = tid * 8 + i * 4;
      int e = idx >> 4, kk = idx & 15;
      float4 v = *(const float4*)(W + (size_t)(e0 + e) * DD + k0 + kk);
      Wt[kk + 0][e] = v.x; Wt[kk + 1][e] = v.y;
      Wt[kk + 2][e] = v.z; Wt[kk + 3][e] = v.w;
    }
#pragma unroll
    for (int i = 0; i < 2; ++i) {
      int idx = tid * 4 + i * 1024;
      int kk = idx >> 7, l = idx & 127;
      *(float4*)&Ut[kk][l] = *(const float4*)(Ub + (size_t)(k0 + kk) * LL + l0 + l);
    }
    __syncthreads();
#pragma unroll
    for (int kk = 0; kk < 16; ++kk) {
      float a[8], bb2[8];
#pragma unroll
      for (int i = 0; i < 4; ++i) { a[i] = Wt[kk][ty * 4 + i]; a[i + 4] = Wt[kk][64 + ty * 4 + i]; }
#pragma unroll
      for (int j = 0; j < 4; ++j) { bb2[j] = Ut[kk][tx * 4 + j]; bb2[j + 4] = Ut[kk][64 + tx * 4 + j]; }
#pragma unroll
      for (int i = 0; i < 8; ++i)
#pragma unroll
        for (int j = 0; j < 8; ++j) acc[i][j] += a[i] * bb2[j];
    }
    __syncthreads();
  }
#pragma unroll
  for (int i = 0; i < 8; ++i) {
    int e = e0 + ((i < 4) ? (ty * 4 + i) : (64 + ty * 4 + (i - 4)));
    float* dst = (e < DD) ? (xpre + ((size_t)b * DD + e) * LL)
                          : (zb   + ((size_t)b * DD + (e - DD)) * LL);
    float4 v0 = make_float4(acc[i][0], acc[i][1], acc[i][2], acc[i][3]);
    float4 v1 = make_float4(acc[i][4], acc[i][5], acc[i][6], acc[i][7]);
    *(float4*)(dst + l0 + tx * 4) = v0;
    *(float4*)(dst + l0 + 64 + tx * 4) = v1;
  }
}

// ---------------- K3: fused depthwise conv (3-tap along d) + x_proj + dt_proj ----------------
__global__ __launch_bounds__(256) void k3_proj(
    const float* __restrict__ xpre,
    const float* __restrict__ cw, const float* __restrict__ cbv_g,
    const float* __restrict__ xpw,  const float* __restrict__ dtw,
    const float* __restrict__ dtb,
    const float* __restrict__ xpwB, const float* __restrict__ dtwB,
    float* __restrict__ gdelta, float* __restrict__ gB, float* __restrict__ gC,
    float* __restrict__ xc_out) {
  __shared__ float xr[258 * 36];          // rows 0 and 257 are zero halo
  __shared__ float dbls[2 * 48 * 33];
  const int l0 = blockIdx.x * 32;
  const int b = blockIdx.y;
  const int tid = threadIdx.x;
  const int j = tid & 31, grp = tid >> 5;

  // stage raw xpre rows 1..256 (float4 coalesced)
  for (int idx = tid; idx < 256 * 8; idx += 256) {
    int row = idx >> 3, q = idx & 7;
    float4 v = *(const float4*)(xpre + ((size_t)b * DD + row) * LL + l0 + q * 4);
    *(float4*)&xr[(row + 1) * 36 + q * 4] = v;
  }
  if (tid < 72) {
    int r = (tid >= 36) ? 257 : 0;
    xr[r * 36 + (tid % 36)] = 0.f;
  }
  __syncthreads();

  // conv weights for this thread's column j (kernel row kh=1 only; H=1 spatial)
  const float w0 = cw[(l0 + j) * 9 + 3];
  const float w1 = cw[(l0 + j) * 9 + 4];
  const float w2 = cw[(l0 + j) * 9 + 5];
  const float cbv = cbv_g[l0 + j];

  float xcreg[32];
#pragma unroll
  for (int i = 0; i < 32; ++i) {
    int d = grp * 32 + i;
    float v = cbv + w1 * xr[(d + 1) * 36 + j] + w0 * xr[d * 36 + j] + w2 * xr[(d + 2) * 36 + j];
    xcreg[i] = v;
    xc_out[((size_t)b * DD + d) * LL + l0 + j] = v;
  }
  __syncthreads();
#pragma unroll
  for (int i = 0; i < 32; ++i) xr[(grp * 32 + i + 1) * 36 + j] = xcreg[i];
  __syncthreads();

  // x_proj both dirs: dbl[k] = sum_d xpw[k][d] * xc[d][j]
  for (int dir = 0; dir < 2; ++dir) {
    const float* wp = dir ? xpwB : xpw;
    float acc[6] = {0.f, 0.f, 0.f, 0.f, 0.f, 0.f};
#pragma unroll 4
    for (int dd = 0; dd < DD; ++dd) {
      float xv = xr[(dd + 1) * 36 + j];
#pragma unroll
      for (int ki = 0; ki < 6; ++ki)
        acc[ki] += wp[(size_t)(grp + ki * 8) * DD + dd] * xv;
    }
#pragma unroll
    for (int ki = 0; ki < 6; ++ki) dbls[(dir * 48 + grp + ki * 8) * 33 + j] = acc[ki];
  }
  __syncthreads();

  // dt_proj + softplus
  for (int dir = 0; dir < 2; ++dir) {
    const float* dw = dir ? dtwB : dtw;
    for (int dd = grp * 32; dd < grp * 32 + 32; ++dd) {
      float acc = 0.f;
#pragma unroll
      for (int r = 0; r < 16; ++r) acc += dw[dd * 16 + r] * dbls[(dir * 48 + r) * 33 + j];
      float delta = softplus_f(acc + dtb[dd]);
      gdelta[(((size_t)dir * BN + b) * DD + dd) * LL + l0 + j] = delta;
    }
  }
  // B, C out
  for (int idx = tid; idx < 2 * 32 * 32; idx += 256) {
    int dir = idx >> 10;
    int rem = idx & 1023;
    int k = rem >> 5, jj = rem & 31;
    float v = dbls[(dir * 48 + 16 + k) * 33 + jj];
    if (k < 16)
      gB[(((size_t)dir * BN + b) * NS + k) * LL + l0 + jj] = v;
    else
      gC[(((size_t)dir * BN + b) * NS + (k - 16)) * LL + l0 + jj] = v;
  }
}

// ---------------- K4: scan pass A — per-chunk q (scan from 0) and P = exp(An*sum(dl)) ----------------
__global__ __launch_bounds__(256) void k4_scanA(
    const float* __restrict__ gdelta, const float* __restrict__ x,
    const float* __restrict__ gB,
    const float* __restrict__ Alog, const float* __restrict__ AlogB,
    float* __restrict__ Pbuf, float* __restrict__ qbuf) {
  __shared__ float sdl[16 * SP];
  __shared__ float sdx[16 * SP];   // delta * u (u flipped for dir=1)
  __shared__ float sB[16 * SP];
  const int s = blockIdx.x;
  const int dbase = blockIdx.y * 16;
  const int dir = blockIdx.z >> 2, b = blockIdx.z & 3;
  const int t0 = s * CT;
  const int tid = threadIdx.x;

  for (int idx = tid; idx < 16 * 32; idx += 256) {
    int row = idx >> 5, q = idx & 31;
    float4 dl = *(const float4*)(gdelta + (((size_t)dir * BN + b) * DD + dbase + row) * LL + t0 + q * 4);
    float4 xv;
    if (dir == 0) {
      xv = *(const float4*)(x + ((size_t)b * DD + dbase + row) * LL + t0 + q * 4);
    } else {
      const float* xrow = x + ((size_t)b * DD + dbase + row) * LL;
      float4 t = *(const float4*)(xrow + (LL - 4 - t0 - q * 4));
      xv = make_float4(t.w, t.z, t.y, t.x);
    }
    *(float4*)&sdl[row * SP + q * 4] = dl;
    *(float4*)&sdx[row * SP + q * 4] =
        make_float4(dl.x * xv.x, dl.y * xv.y, dl.z * xv.z, dl.w * xv.w);
    *(float4*)&sB[row * SP + q * 4] =
        *(const float4*)(gB + (((size_t)dir * BN + b) * NS + row) * LL + t0 + q * 4);
  }
  __syncthreads();

  const int g = tid >> 4, n = tid & 15;
  const int d = dbase + g;
  const float An = -__expf((dir ? AlogB : Alog)[d * NS + n]);
  float h = 0.f, S = 0.f;
#pragma unroll 4
  for (int jb = 0; jb < CT; jb += 4) {
    float4 dl4 = *(float4*)&sdl[g * SP + jb];
    float4 dx4 = *(float4*)&sdx[g * SP + jb];
    float4 B4  = *(float4*)&sB[n * SP + jb];
    h = h * __expf(dl4.x * An) + dx4.x * B4.x;
    h = h * __expf(dl4.y * An) + dx4.y * B4.y;
    h = h * __expf(dl4.z * An) + dx4.z * B4.z;
    h = h * __expf(dl4.w * An) + dx4.w * B4.w;
    S += dl4.x + dl4.y + dl4.z + dl4.w;
  }
  const size_t pidx = ((((size_t)dir * BN + b) * DD + d) * NCH + s) * NS + n;
  Pbuf[pidx] = __expf(An * S);
  qbuf[pidx] = h;
}

// ---------------- K5: middle scan over chunks; hstart overwrites qbuf in place ----------------
__global__ __launch_bounds__(256) void k5_mid(
    const float* __restrict__ Pbuf, float* __restrict__ qbuf) {
  int id = blockIdx.x * 256 + threadIdx.x;   // 32768 = 2*4*256*16
  int n = id & 15;
  int d = (id >> 4) & 255;
  int rb = id >> 12;
  size_t base = (((size_t)rb * DD + d) * NCH) * NS + n;
  float h = 0.f;
  for (int s = 0; s < NCH; ++s) {
    size_t idx = base + (size_t)s * NS;
    float Pv = Pbuf[idx];
    float qv = qbuf[idx];
    qbuf[idx] = h;
    h = h * Pv + qv;
  }
}

// ---------------- K6: scan pass C — replay with h0, LDS-transpose y reduction ----------------
__global__ __launch_bounds__(256) void k6_scanC(
    const float* __restrict__ gdelta, const float* __restrict__ x,
    const float* __restrict__ gB, const float* __restrict__ gC,
    const float* __restrict__ zb,
    const float* __restrict__ Alog, const float* __restrict__ AlogB,
    const float* __restrict__ Dvec, const float* __restrict__ DvecB,
    const float* __restrict__ hstart,
    float* __restrict__ y, float* __restrict__ yb) {
  __shared__ float sdl[16 * SP];
  __shared__ float sx[16 * SP];
  __shared__ float sB[16 * SP];
  __shared__ float sC[16 * SP];
  __shared__ float ylds[16 * 16 * 17];   // [g][n][step-in-batch], stride 17
  const int s = blockIdx.x;
  const int dbase = blockIdx.y * 16;
  const int dir = blockIdx.z >> 2, b = blockIdx.z & 3;
  const int t0 = s * CT;
  const int tid = threadIdx.x;

  for (int idx = tid; idx < 16 * 32; idx += 256) {
    int row = idx >> 5, q = idx & 31;
    *(float4*)&sdl[row * SP + q * 4] =
        *(const float4*)(gdelta + (((size_t)dir * BN + b) * DD + dbase + row) * LL + t0 + q * 4);
    float4 xv;
    if (dir == 0) {
      xv = *(const float4*)(x + ((size_t)b * DD + dbase + row) * LL + t0 + q * 4);
    } else {
      const float* xrow = x + ((size_t)b * DD + dbase + row) * LL;
      float4 t = *(const float4*)(xrow + (LL - 4 - t0 - q * 4));
      xv = make_float4(t.w, t.z, t.y, t.x);
    }
    *(float4*)&sx[row * SP + q * 4] = xv;
    *(float4*)&sB[row * SP + q * 4] =
        *(const float4*)(gB + (((size_t)dir * BN + b) * NS + row) * LL + t0 + q * 4);
    *(float4*)&sC[row * SP + q * 4] =
        *(const float4*)(gC + (((size_t)dir * BN + b) * NS + row) * LL + t0 + q * 4);
  }
  __syncthreads();

  const int g = tid >> 4, n = tid & 15;
  const int d = dbase + g;
  const float An = -__expf((dir ? AlogB : Alog)[d * NS + n]);
  const float Dd = (dir ? DvecB : Dvec)[d];
  const size_t pidx = ((((size_t)dir * BN + b) * DD + d) * NCH + s) * NS + n;
  float h = hstart[pidx];
  float* dst = (dir ? yb : y) + ((size_t)b * DD + d) * LL;
  const float* zrow = zb + ((size_t)b * DD + d) * LL;
  const int yrow = (g * 16 + n) * 17;

  for (int jb = 0; jb < CT; jb += 16) {
#pragma unroll
    for (int q = 0; q < 4; ++q) {
      int j4 = jb + q * 4;
      float4 dl4 = *(float4*)&sdl[g * SP + j4];
      float4 x4  = *(float4*)&sx[g * SP + j4];
      float4 B4  = *(float4*)&sB[n * SP + j4];
      float4 C4  = *(float4*)&sC[n * SP + j4];
      h = h * __expf(dl4.x * An) + (dl4.x * x4.x) * B4.x; ylds[yrow + q * 4 + 0] = h * C4.x;
      h = h * __expf(dl4.y * An) + (dl4.y * x4.y) * B4.y; ylds[yrow + q * 4 + 1] = h * C4.y;
      h = h * __expf(dl4.z * An) + (dl4.z * x4.z) * B4.z; ylds[yrow + q * 4 + 2] = h * C4.z;
      h = h * __expf(dl4.w * An) + (dl4.w * x4.w) * B4.w; ylds[yrow + q * 4 + 3] = h * C4.w;
    }
    // intra-wave transpose reduction: lane n sums over m for step t = jb + n
    float ysum = 0.f;
#pragma unroll
    for (int m = 0; m < 16; ++m) ysum += ylds[(g * 16 + m) * 17 + n];
    int t = jb + n;
    float xv = sx[g * SP + t];
    float zv = zrow[t0 + t];
    dst[t0 + t] = (ysum + Dd * xv) * silu_f(zv);
  }
}

// ---------------- K7: dual LayerNorm over l + double SiLU gate + flip-add ----------------
__global__ __launch_bounds__(256) void k7_final(
    const float* __restrict__ y, const float* __restrict__ yb,
    const float* __restrict__ zb,
    const float* __restrict__ lnw, const float* __restrict__ lnb,
    const float* __restrict__ ln1w, const float* __restrict__ ln1b,
    float* __restrict__ out) {
  __shared__ float sy[LL];
  __shared__ float syb[LL];
  __shared__ float rsum[4][4];
  const int row = blockIdx.x;
  const int tid = threadIdx.x;
  const size_t base = (size_t)row * LL;
  float s1y = 0.f, s2y = 0.f, s1b = 0.f, s2b = 0.f;
  for (int j = tid * 4; j < LL; j += 1024) {
    float4 v = *(const float4*)(y + base + j);
    *(float4*)&sy[j] = v;
    s1y += v.x + v.y + v.z + v.w;
    s2y += v.x * v.x + v.y * v.y + v.z * v.z + v.w * v.w;
    float4 w = *(const float4*)(yb + base + j);
    *(float4*)&syb[j] = w;
    s1b += w.x + w.y + w.z + w.w;
    s2b += w.x * w.x + w.y * w.y + w.z * w.z + w.w * w.w;
  }
#pragma unroll
  for (int m = 1; m < 64; m <<= 1) {
    s1y += __shfl_xor(s1y, m); s2y += __shfl_xor(s2y, m);
    s1b += __shfl_xor(s1b, m); s2b += __shfl_xor(s2b, m);
  }
  int wv = tid >> 6;
  if ((tid & 63) == 0) { rsum[wv][0] = s1y; rsum[wv][1] = s2y; rsum[wv][2] = s1b; rsum[wv][3] = s2b; }
  __syncthreads();
  float t1y = rsum[0][0] + rsum[1][0] + rsum[2][0] + rsum[3][0];
  float t2y = rsum[0][1] + rsum[1][1] + rsum[2][1] + rsum[3][1];
  float t1b = rsum[0][2] + rsum[1][2] + rsum[2][2] + rsum[3][2];
  float t2b = rsum[0][3] + rsum[1][3] + rsum[2][3] + rsum[3][3];
  const float inv = 1.f / (float)LL;
  float mY = t1y * inv; float vY = t2y * inv - mY * mY; float rY = rsqrtf(vY + 1e-5f);
  float mB = t1b * inv; float vB = t2b * inv - mB * mB; float rB = rsqrtf(vB + 1e-5f);
  for (int j = tid; j < LL; j += 256) {
    int jr = LL - 1 - j;
    float a  = (sy[j]  - mY) * rY * lnw[j]   + lnb[j];
    float g1 = silu_f(zb[base + j]);
    float bv = (syb[jr] - mB) * rB * ln1w[jr] + ln1b[jr];
    float g2 = silu_f(zb[base + jr]);
    out[base + j] = a * g1 + bv * g2;
  }
}

extern "C" void kernel_launch(void* const* d_in, const int* in_sizes, int n_in,
                              void* d_out, int out_size, void* d_ws, size_t ws_size,
                              hipStream_t stream) {
  const float* u     = (const float*)d_in[0];
  const float* inw   = (const float*)d_in[1];
  const float* cw    = (const float*)d_in[2];
  const float* cb    = (const float*)d_in[3];
  const float* xpw   = (const float*)d_in[4];
  const float* dtw   = (const float*)d_in[5];
  const float* dtb   = (const float*)d_in[6];
  const float* Alog  = (const float*)d_in[7];
  const float* Dv    = (const float*)d_in[8];
  const float* xpwB  = (const float*)d_in[9];
  const float* dtwB  = (const float*)d_in[10];
  const float* AlogB = (const float*)d_in[11];
  const float* DvB   = (const float*)d_in[12];
  const float* lnw   = (const float*)d_in[13];
  const float* lnb   = (const float*)d_in[14];
  const float* ln1w  = (const float*)d_in[15];
  const float* ln1b  = (const float*)d_in[16];
  float* out = (float*)d_out;

  float* ws = (float*)d_ws;
  const size_t SZ = (size_t)BN * DD * LL;        // 4,194,304 floats
  float* xpre   = ws;                 // dead after k3 -> reused as y
  float* zb     = ws + SZ;
  float* xc     = ws + 2 * SZ;
  float* gdelta = ws + 3 * SZ;        // 2 dirs -> 2*SZ
  float* gB     = ws + 5 * SZ;
  float* gC     = gB + SZ / 8;
  float* Pbuf   = gC + SZ / 8;
  float* qbuf   = Pbuf + SZ / 4;      // becomes hstart after k5_mid
  float* ybuf   = xpre;               // alias
  float* ybbuf  = qbuf + SZ / 4;

  k1_inproj<<<dim3(32, 4, 4), 256, 0, stream>>>(inw, u, xpre, zb);
  k3_proj<<<dim3(128, 4), 256, 0, stream>>>(xpre, cw, cb, xpw, dtw, dtb, xpwB, dtwB,
                                            gdelta, gB, gC, xc);
  k4_scanA<<<dim3(NCH, 16, 8), 256, 0, stream>>>(gdelta, xc, gB, Alog, AlogB, Pbuf, qbuf);
  k5_mid<<<128, 256, 0, stream>>>(Pbuf, qbuf);
  k6_scanC<<<dim3(NCH, 16, 8), 256, 0, stream>>>(gdelta, xc, gB, gC, zb, Alog, AlogB,
                                                 Dv, DvB, qbuf, ybuf, ybbuf);
  k7_final<<<1024, 256, 0, stream>>>(ybuf, ybbuf, zb, lnw, lnb, ln1w, ln1b, out);
}